// Round 5
// baseline (719.130 us; speedup 1.0000x reference)
//
#include <hip/hip_runtime.h>
#include <math.h>

#define DIM 64
#define HEADS 8
#define HIDDEN 256
#define HPAD 132   // 128 j's + 4 pad floats: row stride 132*4B -> bank stride mi*4, 16B aligned

// readlane: broadcast lane `srcLane`'s value to all lanes (srcLane must be wave-uniform)
__device__ __forceinline__ float lane_bcast(float v, int srcLane) {
  return __int_as_float(__builtin_amdgcn_readlane(__float_as_int(v), srcLane));
}

// ---------------- prep: fold linear chains into combined weights ----------------
__global__ void prep_kernel(
    const float* __restrict__ w_in, const float* __restrict__ b_in,
    const float* __restrict__ w_edge, const float* __restrict__ b_edge,
    const float* __restrict__ w_att_u, const float* __restrict__ b_att_u,
    const float* __restrict__ w_att_v,
    const float* __restrict__ w_att_e, const float* __restrict__ b_att_e,
    float* __restrict__ Waug, float* __restrict__ baug,
    float* __restrict__ wcc, float* __restrict__ bcc)
{
  int t = threadIdx.x; // 256 threads
  if (t < 64) {
    for (int j = 0; j < 64; ++j) Waug[t*80 + j] = w_in[t*64 + j];
    for (int hh = 0; hh < 8; ++hh) {
      float a = 0.f, b = 0.f;
      for (int j = 0; j < 64; ++j) {
        float w = w_in[t*64 + j];
        a += w * w_att_u[j*8 + hh];
        b += w * w_att_v[j*8 + hh];
      }
      Waug[t*80 + 64 + hh] = a;
      Waug[t*80 + 72 + hh] = b;
    }
  } else if (t < 128) {
    int j = t - 64;
    baug[j] = b_in[j];
  } else if (t < 136) {
    int hh = t - 128;
    float a = b_att_u[hh];
    for (int k = 0; k < 64; ++k) a += b_in[k] * w_att_u[k*8 + hh];
    baug[64 + hh] = a;
  } else if (t < 144) {
    int hh = t - 136;
    float a = 0.f;
    for (int k = 0; k < 64; ++k) a += b_in[k] * w_att_v[k*8 + hh];
    baug[72 + hh] = a;
  } else if (t < 160) {
    int c = (t - 144) >> 3, hh = (t - 144) & 7;
    float a = 0.f;
    for (int j = 0; j < 64; ++j) a += w_edge[c*64 + j] * w_att_e[j*8 + hh];
    wcc[c*8 + hh] = a;
  } else if (t < 168) {
    int hh = t - 160;
    float a = b_att_e[hh];
    for (int j = 0; j < 64; ++j) a += b_edge[j] * w_att_e[j*8 + hh];
    bcc[hh] = a;
  }
}

// ---------------- node GEMM: [N,64] @ [64,80] -> h, su, sv ----------------
// Wave per 8 nodes. Lane owns output column `lane` (h) and column 64+lane
// (su|sv, lanes 0..15). x broadcast via v_readlane.
__global__ __launch_bounds__(256) void node_gemm_kernel(
    const float* __restrict__ x,
    const float* __restrict__ Waug, const float* __restrict__ baug,
    float* __restrict__ hbuf, float* __restrict__ subuf, float* __restrict__ svbuf,
    int n_nodes)
{
  const int wid = threadIdx.x >> 6;
  const int lane = threadIdx.x & 63;
  const long nbase = (long)blockIdx.x * 32 + wid * 8;

  float xr[8];
  #pragma unroll
  for (int m = 0; m < 8; ++m) {
    long n = nbase + m; if (n >= n_nodes) n = n_nodes - 1;
    xr[m] = x[n*DIM + lane];          // coalesced 256B row read
  }
  const float bmain = baug[lane];
  const float bext  = (lane < 16) ? baug[64 + lane] : 0.f;
  float acc[8], acc2[8];
  #pragma unroll
  for (int m = 0; m < 8; ++m) { acc[m] = bmain; acc2[m] = 0.f; }

  #pragma unroll 16
  for (int k = 0; k < 64; ++k) {
    float wmain = Waug[k*80 + lane];                       // coalesced
    float wext  = (lane < 16) ? Waug[k*80 + 64 + lane] : 0.f;
    #pragma unroll
    for (int m = 0; m < 8; ++m) {
      float xk = lane_bcast(xr[m], k);
      acc[m]  += xk * wmain;
      acc2[m] += xk * wext;
    }
  }
  #pragma unroll
  for (int m = 0; m < 8; ++m) {
    long n = nbase + m;
    if (n >= n_nodes) continue;
    hbuf[n*DIM + lane] = acc[m];
    if (lane < 8)       subuf[n*8 + lane]     = acc2[m] + bext;
    else if (lane < 16) svbuf[n*8 + lane - 8] = acc2[m] + bext;
  }
}

// ---------------- CSR build ----------------
__global__ void hist_kernel(const int* __restrict__ dst, int* __restrict__ deg, int n_edges) {
  int i = blockIdx.x * blockDim.x + threadIdx.x;
  if (i < n_edges) atomicAdd(&deg[dst[i]], 1);
}

__global__ void alloc_kernel(const int* __restrict__ deg, int* __restrict__ off,
                             int* __restrict__ counter, int n_nodes) {
  int i = blockIdx.x * blockDim.x + threadIdx.x;
  int lane = threadIdx.x & 63;
  int d = (i < n_nodes) ? deg[i] : 0;
  int pre = d;
  #pragma unroll
  for (int s = 1; s < 64; s <<= 1) {
    int v = __shfl_up(pre, s, 64);
    if (lane >= s) pre += v;
  }
  int tot = __shfl(pre, 63, 64);
  int base = 0;
  if (lane == 0) base = atomicAdd(counter, tot);
  base = __shfl(base, 0, 64);
  if (i < n_nodes) off[i] = base + pre - d;
}

__global__ void scatter_kernel(const int* __restrict__ dst, const int* __restrict__ off,
                               int* __restrict__ pos, int* __restrict__ csr, int n_edges) {
  int i = blockIdx.x * blockDim.x + threadIdx.x;
  if (i < n_edges) {
    int d = dst[i];
    int p = atomicAdd(&pos[d], 1);
    csr[off[d] + p] = i;
  }
}

// ---------------- attention gather: 16-lane group per dst node ----------------
// Wave handles 4 nodes (one per 16-lane group). Score phase: lane sub handles
// edge sub of the chunk (deg avg 16 -> high lane utilization). Message phase:
// lane owns 4 output dims (float4 h-row reads, 256B/group coalesced).
__global__ __launch_bounds__(256) void attn_kernel(
    const int* __restrict__ src, const int* __restrict__ csr,
    const int* __restrict__ off, const int* __restrict__ deg,
    const float* __restrict__ edge_feat,
    const float* __restrict__ hbuf, const float* __restrict__ subuf,
    const float* __restrict__ svbuf,
    const float* __restrict__ wcc, const float* __restrict__ bcc,
    float* __restrict__ agg, int n_nodes)
{
  __shared__ float pbuf[4][4][16][8];   // 8 KB
  __shared__ int   sbuf[4][4][16];      // 1 KB
  const int wid = threadIdx.x >> 6;
  const int lane = threadIdx.x & 63;
  const int g = lane >> 4, sub = lane & 15;
  const long n = (long)blockIdx.x * 16 + wid * 4 + g;
  const bool valid = (n < n_nodes);
  const long nc = valid ? n : (long)(n_nodes - 1);
  const int ebase = off[nc];
  const int d = valid ? deg[nc] : 0;
  const int hb = (sub & 1) * 4;   // head base for this lane's 4 dims

  float svn[8], c0v[8], c1v[8], cbv[8];
  {
    const float4* svp = (const float4*)(svbuf + nc*8);
    float4 s0 = svp[0], s1 = svp[1];
    svn[0]=s0.x; svn[1]=s0.y; svn[2]=s0.z; svn[3]=s0.w;
    svn[4]=s1.x; svn[5]=s1.y; svn[6]=s1.z; svn[7]=s1.w;
    #pragma unroll
    for (int hh = 0; hh < 8; ++hh) {
      c0v[hh] = wcc[hh]; c1v[hh] = wcc[8+hh]; cbv[hh] = bcc[hh];
    }
  }
  float m8[8], den8[8];
  #pragma unroll
  for (int hh = 0; hh < 8; ++hh) { m8[hh] = -INFINITY; den8[hh] = 0.f; }
  float4 msg = make_float4(0.f, 0.f, 0.f, 0.f);

  for (int c0 = 0; c0 < d; c0 += 16) {
    const int cnt = min(16, d - c0);
    float sc[8];
    int sid = 0;
    if (sub < cnt) {
      const int eid = csr[ebase + c0 + sub];
      sid = src[eid];
      const float2 ef = *(const float2*)(edge_feat + (long)eid*2);
      const float4* sup = (const float4*)(subuf + (long)sid*8);
      float4 u0 = sup[0], u1 = sup[1];
      float suv[8] = {u0.x,u0.y,u0.z,u0.w,u1.x,u1.y,u1.z,u1.w};
      #pragma unroll
      for (int hh = 0; hh < 8; ++hh) {
        float v = suv[hh] + svn[hh] + ef.x*c0v[hh] + ef.y*c1v[hh] + cbv[hh];
        sc[hh] = (v > 0.f) ? v : 0.2f*v;   // leaky_relu 0.2
      }
    } else {
      #pragma unroll
      for (int hh = 0; hh < 8; ++hh) sc[hh] = -INFINITY;
    }
    // group max (xor masks <16 stay within the 16-lane group)
    float cm[8];
    #pragma unroll
    for (int hh = 0; hh < 8; ++hh) cm[hh] = sc[hh];
    #pragma unroll
    for (int sft = 8; sft >= 1; sft >>= 1) {
      #pragma unroll
      for (int hh = 0; hh < 8; ++hh)
        cm[hh] = fmaxf(cm[hh], __shfl_xor(cm[hh], sft, 64));
    }
    // online softmax update
    float f[8], pv[8];
    #pragma unroll
    for (int hh = 0; hh < 8; ++hh) {
      float nm = fmaxf(m8[hh], cm[hh]);
      f[hh] = __expf(m8[hh] - nm);
      pv[hh] = __expf(sc[hh] - nm);
      m8[hh] = nm;
    }
    if (sub < cnt) {
      float4* pp = (float4*)&pbuf[wid][g][sub][0];
      pp[0] = make_float4(pv[0], pv[1], pv[2], pv[3]);
      pp[1] = make_float4(pv[4], pv[5], pv[6], pv[7]);
      sbuf[wid][g][sub] = sid;
    }
    // group denominator
    float q[8];
    #pragma unroll
    for (int hh = 0; hh < 8; ++hh) q[hh] = pv[hh];
    #pragma unroll
    for (int sft = 8; sft >= 1; sft >>= 1) {
      #pragma unroll
      for (int hh = 0; hh < 8; ++hh)
        q[hh] += __shfl_xor(q[hh], sft, 64);
    }
    #pragma unroll
    for (int hh = 0; hh < 8; ++hh) den8[hh] = den8[hh]*f[hh] + q[hh];
    // rescale msg: dims sub*4+i use head hb+i (hb runtime -> select, not index)
    {
      float f0 = (sub & 1) ? f[4] : f[0];
      float f1 = (sub & 1) ? f[5] : f[1];
      float f2 = (sub & 1) ? f[6] : f[2];
      float f3 = (sub & 1) ? f[7] : f[3];
      msg.x *= f0; msg.y *= f1; msg.z *= f2; msg.w *= f3;
    }
    // wave-private LDS: waitcnt sufficient (no cross-wave sharing)
    asm volatile("s_waitcnt lgkmcnt(0)" ::: "memory");

    // message accumulation: lane owns dims sub*4..+3
    #pragma unroll 2
    for (int e2 = 0; e2 < cnt; ++e2) {
      int sidu = sbuf[wid][g][e2];
      float4 p = *(const float4*)&pbuf[wid][g][e2][hb];   // runtime LDS addr ok
      float4 hv = *(const float4*)&hbuf[(long)sidu*DIM + sub*4];
      msg.x += hv.x*p.x; msg.y += hv.y*p.y; msg.z += hv.z*p.z; msg.w += hv.w*p.w;
    }
  }
  float d0 = (sub & 1) ? den8[4] : den8[0];
  float d1 = (sub & 1) ? den8[5] : den8[1];
  float d2 = (sub & 1) ? den8[6] : den8[2];
  float d3 = (sub & 1) ? den8[7] : den8[3];
  if (valid) {
    float4 o;
    o.x = msg.x / fmaxf(d0, 1e-12f);
    o.y = msg.y / fmaxf(d1, 1e-12f);
    o.z = msg.z / fmaxf(d2, 1e-12f);
    o.w = msg.w / fmaxf(d3, 1e-12f);
    *(float4*)(agg + n*DIM + sub*4) = o;
  }
}

// ---------------- FFN: gelu(agg@w1+b1)@w2+b2 ----------------
// Wave per 8 nodes. Phase 1: lane owns j-slice [lane*4, +4) across 8 nodes
// (readlane-broadcast x, coalesced 1KB w1 rows). Split-hid transpose through
// 16.5KB LDS (two 128-j passes; wave-private, lgkmcnt only). Phase 2: lane
// owns (node mi=lane>>3, dim-octet dg=lane&7): per-lane-distinct ds_read_b128
// (64 total/wave vs 512 broadcast reads) + coalesced w2 loads.
__global__ __launch_bounds__(256) void ffn_kernel(
    const float* __restrict__ agg,
    const float* __restrict__ w1, const float* __restrict__ b1,
    const float* __restrict__ w2, const float* __restrict__ b2,
    float* __restrict__ out, int n_nodes)
{
  __shared__ float hid[4][8][HPAD];   // 16.5 KB
  const int wid = threadIdx.x >> 6;
  const int lane = threadIdx.x & 63;
  const long nbase = (long)blockIdx.x * 32 + wid * 8;

  // ---- phase 1 ----
  float xr[8];
  #pragma unroll
  for (int m = 0; m < 8; ++m) {
    long n = nbase + m; if (n >= n_nodes) n = n_nodes - 1;
    xr[m] = agg[n*DIM + lane];
  }
  float4 bb = *(const float4*)(b1 + lane*4);
  float h[8][4];
  #pragma unroll
  for (int m = 0; m < 8; ++m) { h[m][0]=bb.x; h[m][1]=bb.y; h[m][2]=bb.z; h[m][3]=bb.w; }

  #pragma unroll 8
  for (int k = 0; k < 64; ++k) {
    float4 w = *(const float4*)(w1 + k*HIDDEN + lane*4);
    #pragma unroll
    for (int m = 0; m < 8; ++m) {
      float xk = lane_bcast(xr[m], k);
      h[m][0] += xk*w.x; h[m][1] += xk*w.y; h[m][2] += xk*w.z; h[m][3] += xk*w.w;
    }
  }
  #pragma unroll
  for (int m = 0; m < 8; ++m) {
    #pragma unroll
    for (int i = 0; i < 4; ++i)
      h[m][i] = 0.5f*h[m][i]*(1.0f + erff(h[m][i]*0.70710678118654752f));
  }

  // ---- stage lower half (j < 128): lanes 0..31 ----
  if (lane < 32) {
    #pragma unroll
    for (int m = 0; m < 8; ++m)
      *(float4*)&hid[wid][m][lane*4] = make_float4(h[m][0], h[m][1], h[m][2], h[m][3]);
  }
  asm volatile("" ::: "memory");
  asm volatile("s_waitcnt lgkmcnt(0)" ::: "memory");

  // ---- phase 2 ----
  const int mi = lane >> 3, dg = lane & 7;
  float4 accA = *(const float4*)(b2 + dg*8);
  float4 accB = *(const float4*)(b2 + dg*8 + 4);

  // pass A: j in [0, 128)
  #pragma unroll 4
  for (int jc = 0; jc < 32; ++jc) {
    float4 hv = *(const float4*)&hid[wid][mi][jc*4];
    float hvv[4] = {hv.x, hv.y, hv.z, hv.w};
    #pragma unroll
    for (int jj = 0; jj < 4; ++jj) {
      int j = jc*4 + jj;
      float4 wA = *(const float4*)(w2 + j*DIM + dg*8);
      float4 wB = *(const float4*)(w2 + j*DIM + dg*8 + 4);
      float hvj = hvv[jj];
      accA.x += hvj*wA.x; accA.y += hvj*wA.y; accA.z += hvj*wA.z; accA.w += hvj*wA.w;
      accB.x += hvj*wB.x; accB.y += hvj*wB.y; accB.z += hvj*wB.z; accB.w += hvj*wB.w;
    }
  }

  // ---- stage upper half (j in [128,256)): lanes 32..63 ----
  // In-wave DS ordering guarantees pass-A reads complete before these writes;
  // fences stop compiler reordering.
  asm volatile("" ::: "memory");
  if (lane >= 32) {
    #pragma unroll
    for (int m = 0; m < 8; ++m)
      *(float4*)&hid[wid][m][(lane-32)*4] = make_float4(h[m][0], h[m][1], h[m][2], h[m][3]);
  }
  asm volatile("" ::: "memory");
  asm volatile("s_waitcnt lgkmcnt(0)" ::: "memory");

  // pass B: j in [128, 256)
  #pragma unroll 4
  for (int jc = 0; jc < 32; ++jc) {
    float4 hv = *(const float4*)&hid[wid][mi][jc*4];
    float hvv[4] = {hv.x, hv.y, hv.z, hv.w};
    #pragma unroll
    for (int jj = 0; jj < 4; ++jj) {
      int j = 128 + jc*4 + jj;
      float4 wA = *(const float4*)(w2 + j*DIM + dg*8);
      float4 wB = *(const float4*)(w2 + j*DIM + dg*8 + 4);
      float hvj = hvv[jj];
      accA.x += hvj*wA.x; accA.y += hvj*wA.y; accA.z += hvj*wA.z; accA.w += hvj*wA.w;
      accB.x += hvj*wB.x; accB.y += hvj*wB.y; accB.z += hvj*wB.z; accB.w += hvj*wB.w;
    }
  }

  // ---- store: lane owns node mi, dims [dg*8, dg*8+8) ----
  long n = nbase + mi;
  if (n < n_nodes) {
    *(float4*)(out + n*DIM + dg*8)     = accA;
    *(float4*)(out + n*DIM + dg*8 + 4) = accB;
  }
}

// ---------------- launch ----------------
extern "C" void kernel_launch(void* const* d_in, const int* in_sizes, int n_in,
                              void* d_out, int out_size, void* d_ws, size_t ws_size,
                              hipStream_t stream)
{
  const float* x         = (const float*)d_in[0];
  const float* edge_feat = (const float*)d_in[1];
  const float* w_in      = (const float*)d_in[2];
  const float* b_in      = (const float*)d_in[3];
  const float* w_edge    = (const float*)d_in[4];
  const float* b_edge    = (const float*)d_in[5];
  const float* w_att_u   = (const float*)d_in[6];
  const float* b_att_u   = (const float*)d_in[7];
  const float* w_att_v   = (const float*)d_in[8];
  const float* w_att_e   = (const float*)d_in[9];
  const float* b_att_e   = (const float*)d_in[10];
  const float* w_ff1     = (const float*)d_in[11];
  const float* b_ff1     = (const float*)d_in[12];
  const float* w_ff2     = (const float*)d_in[13];
  const float* b_ff2     = (const float*)d_in[14];
  const int*   src       = (const int*)d_in[15];
  const int*   dst       = (const int*)d_in[16];
  float* out = (float*)d_out;

  const int n_nodes = in_sizes[0] / DIM;
  const int n_edges = in_sizes[15];

  char* p = (char*)d_ws;
  auto alloc_f = [&](size_t cnt) { float* r = (float*)p; p += ((cnt*4 + 255) & ~(size_t)255); return r; };
  auto alloc_i = [&](size_t cnt) { int* r = (int*)p;   p += ((cnt*4 + 255) & ~(size_t)255); return r; };
  float* Waug  = alloc_f(64*80);
  float* baug  = alloc_f(80);
  float* wcc   = alloc_f(16);
  float* bcc   = alloc_f(8);
  float* hbuf  = alloc_f((size_t)n_nodes*DIM);
  float* subuf = alloc_f((size_t)n_nodes*8);
  float* svbuf = alloc_f((size_t)n_nodes*8);
  float* aggb  = alloc_f((size_t)n_nodes*DIM);
  int* deg     = alloc_i(n_nodes);
  int* pos     = alloc_i(n_nodes);
  int* counter = alloc_i(64);
  int* offb    = alloc_i(n_nodes);
  int* csr     = alloc_i(n_edges);

  // zero deg, pos, counter in one shot (contiguous in the layout)
  hipMemsetAsync(deg, 0, (size_t)((char*)offb - (char*)deg), stream);

  hipLaunchKernelGGL(prep_kernel, dim3(1), dim3(256), 0, stream,
      w_in, b_in, w_edge, b_edge, w_att_u, b_att_u, w_att_v, w_att_e, b_att_e,
      Waug, baug, wcc, bcc);

  hipLaunchKernelGGL(node_gemm_kernel, dim3((n_nodes+31)/32), dim3(256), 0, stream,
      x, Waug, baug, hbuf, subuf, svbuf, n_nodes);

  hipLaunchKernelGGL(hist_kernel, dim3((n_edges+255)/256), dim3(256), 0, stream,
      dst, deg, n_edges);
  hipLaunchKernelGGL(alloc_kernel, dim3((n_nodes+255)/256), dim3(256), 0, stream,
      deg, offb, counter, n_nodes);
  hipLaunchKernelGGL(scatter_kernel, dim3((n_edges+255)/256), dim3(256), 0, stream,
      dst, offb, pos, csr, n_edges);

  hipLaunchKernelGGL(attn_kernel, dim3((n_nodes+15)/16), dim3(256), 0, stream,
      src, csr, offb, deg, edge_feat, hbuf, subuf, svbuf, wcc, bcc, aggb, n_nodes);

  hipLaunchKernelGGL(ffn_kernel, dim3((n_nodes+31)/32), dim3(256), 0, stream,
      aggb, w_ff1, b_ff1, w_ff2, b_ff2, out, n_nodes);
}

// Round 6
// 632.168 us; speedup vs baseline: 1.1376x; 1.1376x over previous
//
#include <hip/hip_runtime.h>
#include <math.h>

#define DIM 64
#define HEADS 8
#define HIDDEN 256

// readlane: broadcast lane `srcLane`'s value to all lanes (srcLane must be wave-uniform)
__device__ __forceinline__ float lane_bcast(float v, int srcLane) {
  return __int_as_float(__builtin_amdgcn_readlane(__float_as_int(v), srcLane));
}

// ---------------- prep: fold linear chains into combined weights ----------------
__global__ void prep_kernel(
    const float* __restrict__ w_in, const float* __restrict__ b_in,
    const float* __restrict__ w_edge, const float* __restrict__ b_edge,
    const float* __restrict__ w_att_u, const float* __restrict__ b_att_u,
    const float* __restrict__ w_att_v,
    const float* __restrict__ w_att_e, const float* __restrict__ b_att_e,
    float* __restrict__ Waug, float* __restrict__ baug,
    float* __restrict__ wcc, float* __restrict__ bcc)
{
  int t = threadIdx.x; // 256 threads
  if (t < 64) {
    for (int j = 0; j < 64; ++j) Waug[t*80 + j] = w_in[t*64 + j];
    for (int hh = 0; hh < 8; ++hh) {
      float a = 0.f, b = 0.f;
      for (int j = 0; j < 64; ++j) {
        float w = w_in[t*64 + j];
        a += w * w_att_u[j*8 + hh];
        b += w * w_att_v[j*8 + hh];
      }
      Waug[t*80 + 64 + hh] = a;
      Waug[t*80 + 72 + hh] = b;
    }
  } else if (t < 128) {
    int j = t - 64;
    baug[j] = b_in[j];
  } else if (t < 136) {
    int hh = t - 128;
    float a = b_att_u[hh];
    for (int k = 0; k < 64; ++k) a += b_in[k] * w_att_u[k*8 + hh];
    baug[64 + hh] = a;
  } else if (t < 144) {
    int hh = t - 136;
    float a = 0.f;
    for (int k = 0; k < 64; ++k) a += b_in[k] * w_att_v[k*8 + hh];
    baug[72 + hh] = a;
  } else if (t < 160) {
    int c = (t - 144) >> 3, hh = (t - 144) & 7;
    float a = 0.f;
    for (int j = 0; j < 64; ++j) a += w_edge[c*64 + j] * w_att_e[j*8 + hh];
    wcc[c*8 + hh] = a;
  } else if (t < 168) {
    int hh = t - 160;
    float a = b_att_e[hh];
    for (int j = 0; j < 64; ++j) a += b_edge[j] * w_att_e[j*8 + hh];
    bcc[hh] = a;
  }
}

// ---------------- node GEMM: [N,64] @ [64,80] -> h, su, sv ----------------
// Wave per 8 nodes; lane owns output column. (readlane pattern kept as the
// control for the new s_load kernels below.)
__global__ __launch_bounds__(256) void node_gemm_kernel(
    const float* __restrict__ x,
    const float* __restrict__ Waug, const float* __restrict__ baug,
    float* __restrict__ hbuf, float* __restrict__ subuf, float* __restrict__ svbuf,
    int n_nodes)
{
  const int wid = threadIdx.x >> 6;
  const int lane = threadIdx.x & 63;
  const long nbase = (long)blockIdx.x * 32 + wid * 8;

  float xr[8];
  #pragma unroll
  for (int m = 0; m < 8; ++m) {
    long n = nbase + m; if (n >= n_nodes) n = n_nodes - 1;
    xr[m] = x[n*DIM + lane];          // coalesced 256B row read
  }
  const float bmain = baug[lane];
  const float bext  = (lane < 16) ? baug[64 + lane] : 0.f;
  float acc[8], acc2[8];
  #pragma unroll
  for (int m = 0; m < 8; ++m) { acc[m] = bmain; acc2[m] = 0.f; }

  #pragma unroll 16
  for (int k = 0; k < 64; ++k) {
    float wmain = Waug[k*80 + lane];                       // coalesced
    float wext  = (lane < 16) ? Waug[k*80 + 64 + lane] : 0.f;
    #pragma unroll
    for (int m = 0; m < 8; ++m) {
      float xk = lane_bcast(xr[m], k);
      acc[m]  += xk * wmain;
      acc2[m] += xk * wext;
    }
  }
  #pragma unroll
  for (int m = 0; m < 8; ++m) {
    long n = nbase + m;
    if (n >= n_nodes) continue;
    hbuf[n*DIM + lane] = acc[m];
    if (lane < 8)       subuf[n*8 + lane]     = acc2[m] + bext;
    else if (lane < 16) svbuf[n*8 + lane - 8] = acc2[m] + bext;
  }
}

// ---------------- CSR build ----------------
__global__ void hist_kernel(const int* __restrict__ dst, int* __restrict__ deg, int n_edges) {
  int i = blockIdx.x * blockDim.x + threadIdx.x;
  if (i < n_edges) atomicAdd(&deg[dst[i]], 1);
}

__global__ void alloc_kernel(const int* __restrict__ deg, int* __restrict__ off,
                             int* __restrict__ counter, int n_nodes) {
  int i = blockIdx.x * blockDim.x + threadIdx.x;
  int lane = threadIdx.x & 63;
  int d = (i < n_nodes) ? deg[i] : 0;
  int pre = d;
  #pragma unroll
  for (int s = 1; s < 64; s <<= 1) {
    int v = __shfl_up(pre, s, 64);
    if (lane >= s) pre += v;
  }
  int tot = __shfl(pre, 63, 64);
  int base = 0;
  if (lane == 0) base = atomicAdd(counter, tot);
  base = __shfl(base, 0, 64);
  if (i < n_nodes) off[i] = base + pre - d;
}

__global__ void scatter_kernel(const int* __restrict__ dst, const int* __restrict__ off,
                               int* __restrict__ pos, int* __restrict__ csr, int n_edges) {
  int i = blockIdx.x * blockDim.x + threadIdx.x;
  if (i < n_edges) {
    int d = dst[i];
    int p = atomicAdd(&pos[d], 1);
    csr[off[d] + p] = i;
  }
}

// ---------------- attention gather: 16-lane group per dst node ----------------
__global__ __launch_bounds__(256) void attn_kernel(
    const int* __restrict__ src, const int* __restrict__ csr,
    const int* __restrict__ off, const int* __restrict__ deg,
    const float* __restrict__ edge_feat,
    const float* __restrict__ hbuf, const float* __restrict__ subuf,
    const float* __restrict__ svbuf,
    const float* __restrict__ wcc, const float* __restrict__ bcc,
    float* __restrict__ agg, int n_nodes)
{
  __shared__ float pbuf[4][4][16][8];   // 8 KB
  __shared__ int   sbuf[4][4][16];      // 1 KB
  const int wid = threadIdx.x >> 6;
  const int lane = threadIdx.x & 63;
  const int g = lane >> 4, sub = lane & 15;
  const long n = (long)blockIdx.x * 16 + wid * 4 + g;
  const bool valid = (n < n_nodes);
  const long nc = valid ? n : (long)(n_nodes - 1);
  const int ebase = off[nc];
  const int d = valid ? deg[nc] : 0;
  const int hb = (sub & 1) * 4;   // head base for this lane's 4 dims

  float svn[8], c0v[8], c1v[8], cbv[8];
  {
    const float4* svp = (const float4*)(svbuf + nc*8);
    float4 s0 = svp[0], s1 = svp[1];
    svn[0]=s0.x; svn[1]=s0.y; svn[2]=s0.z; svn[3]=s0.w;
    svn[4]=s1.x; svn[5]=s1.y; svn[6]=s1.z; svn[7]=s1.w;
    #pragma unroll
    for (int hh = 0; hh < 8; ++hh) {
      c0v[hh] = wcc[hh]; c1v[hh] = wcc[8+hh]; cbv[hh] = bcc[hh];
    }
  }
  float m8[8], den8[8];
  #pragma unroll
  for (int hh = 0; hh < 8; ++hh) { m8[hh] = -INFINITY; den8[hh] = 0.f; }
  float4 msg = make_float4(0.f, 0.f, 0.f, 0.f);

  for (int c0 = 0; c0 < d; c0 += 16) {
    const int cnt = min(16, d - c0);
    float sc[8];
    int sid = 0;
    if (sub < cnt) {
      const int eid = csr[ebase + c0 + sub];
      sid = src[eid];
      const float2 ef = *(const float2*)(edge_feat + (long)eid*2);
      const float4* sup = (const float4*)(subuf + (long)sid*8);
      float4 u0 = sup[0], u1 = sup[1];
      float suv[8] = {u0.x,u0.y,u0.z,u0.w,u1.x,u1.y,u1.z,u1.w};
      #pragma unroll
      for (int hh = 0; hh < 8; ++hh) {
        float v = suv[hh] + svn[hh] + ef.x*c0v[hh] + ef.y*c1v[hh] + cbv[hh];
        sc[hh] = (v > 0.f) ? v : 0.2f*v;   // leaky_relu 0.2
      }
    } else {
      #pragma unroll
      for (int hh = 0; hh < 8; ++hh) sc[hh] = -INFINITY;
    }
    // group max (xor masks <16 stay within the 16-lane group)
    float cm[8];
    #pragma unroll
    for (int hh = 0; hh < 8; ++hh) cm[hh] = sc[hh];
    #pragma unroll
    for (int sft = 8; sft >= 1; sft >>= 1) {
      #pragma unroll
      for (int hh = 0; hh < 8; ++hh)
        cm[hh] = fmaxf(cm[hh], __shfl_xor(cm[hh], sft, 64));
    }
    // online softmax update
    float f[8], pv[8];
    #pragma unroll
    for (int hh = 0; hh < 8; ++hh) {
      float nm = fmaxf(m8[hh], cm[hh]);
      f[hh] = __expf(m8[hh] - nm);
      pv[hh] = __expf(sc[hh] - nm);
      m8[hh] = nm;
    }
    if (sub < cnt) {
      float4* pp = (float4*)&pbuf[wid][g][sub][0];
      pp[0] = make_float4(pv[0], pv[1], pv[2], pv[3]);
      pp[1] = make_float4(pv[4], pv[5], pv[6], pv[7]);
      sbuf[wid][g][sub] = sid;
    }
    // group denominator
    float q[8];
    #pragma unroll
    for (int hh = 0; hh < 8; ++hh) q[hh] = pv[hh];
    #pragma unroll
    for (int sft = 8; sft >= 1; sft >>= 1) {
      #pragma unroll
      for (int hh = 0; hh < 8; ++hh)
        q[hh] += __shfl_xor(q[hh], sft, 64);
    }
    #pragma unroll
    for (int hh = 0; hh < 8; ++hh) den8[hh] = den8[hh]*f[hh] + q[hh];
    // rescale msg: dims sub*4+i use head hb+i
    {
      float f0 = (sub & 1) ? f[4] : f[0];
      float f1 = (sub & 1) ? f[5] : f[1];
      float f2 = (sub & 1) ? f[6] : f[2];
      float f3 = (sub & 1) ? f[7] : f[3];
      msg.x *= f0; msg.y *= f1; msg.z *= f2; msg.w *= f3;
    }
    // wave-private LDS: waitcnt sufficient (no cross-wave sharing)
    asm volatile("s_waitcnt lgkmcnt(0)" ::: "memory");

    // message accumulation: lane owns dims sub*4..+3
    #pragma unroll 2
    for (int e2 = 0; e2 < cnt; ++e2) {
      int sidu = sbuf[wid][g][e2];
      float4 p = *(const float4*)&pbuf[wid][g][e2][hb];
      float4 hv = *(const float4*)&hbuf[(long)sidu*DIM + sub*4];
      msg.x += hv.x*p.x; msg.y += hv.y*p.y; msg.z += hv.z*p.z; msg.w += hv.w*p.w;
    }
  }
  float d0 = (sub & 1) ? den8[4] : den8[0];
  float d1 = (sub & 1) ? den8[5] : den8[1];
  float d2 = (sub & 1) ? den8[6] : den8[2];
  float d3 = (sub & 1) ? den8[7] : den8[3];
  if (valid) {
    float4 o;
    o.x = msg.x / fmaxf(d0, 1e-12f);
    o.y = msg.y / fmaxf(d1, 1e-12f);
    o.z = msg.z / fmaxf(d2, 1e-12f);
    o.w = msg.w / fmaxf(d3, 1e-12f);
    *(float4*)(agg + n*DIM + sub*4) = o;
  }
}

// ---------------- FFN split: activations via SGPR (scalar loads) ----------------
// ffn1: g = gelu(agg @ w1 + b1).  Wave per 8 nodes; lane owns 4 hidden cols.
// agg rows are wave-uniform pointers -> scalar (s_load) reads feed FMAs as the
// SGPR operand; w1 rows are coalesced 1KB float4 loads. No LDS, no readlane.
__global__ __launch_bounds__(256) void ffn1_kernel(
    const float* __restrict__ agg,
    const float* __restrict__ w1, const float* __restrict__ b1,
    float* __restrict__ g, int n_nodes)
{
  const int wid  = __builtin_amdgcn_readfirstlane(threadIdx.x >> 6);  // wave-uniform
  const int lane = threadIdx.x & 63;
  const long nbase = (long)blockIdx.x * 32 + wid * 8;

  const float* xrow[8];
  #pragma unroll
  for (int m = 0; m < 8; ++m) {
    long n = nbase + m; if (n >= n_nodes) n = n_nodes - 1;
    xrow[m] = agg + n*DIM;            // uniform pointer -> scalar loads
  }
  float4 bb = *(const float4*)(b1 + lane*4);
  float h[8][4];
  #pragma unroll
  for (int m = 0; m < 8; ++m) { h[m][0]=bb.x; h[m][1]=bb.y; h[m][2]=bb.z; h[m][3]=bb.w; }

  #pragma unroll 8
  for (int k = 0; k < 64; ++k) {
    float4 w = *(const float4*)(w1 + k*HIDDEN + lane*4);   // coalesced 1KB
    #pragma unroll
    for (int m = 0; m < 8; ++m) {
      float xk = xrow[m][k];                               // SGPR operand
      h[m][0] += xk*w.x; h[m][1] += xk*w.y; h[m][2] += xk*w.z; h[m][3] += xk*w.w;
    }
  }
  #pragma unroll
  for (int m = 0; m < 8; ++m) {
    long n = nbase + m;
    if (n >= n_nodes) continue;
    float4 o;
    o.x = 0.5f*h[m][0]*(1.0f + erff(h[m][0]*0.70710678118654752f));
    o.y = 0.5f*h[m][1]*(1.0f + erff(h[m][1]*0.70710678118654752f));
    o.z = 0.5f*h[m][2]*(1.0f + erff(h[m][2]*0.70710678118654752f));
    o.w = 0.5f*h[m][3]*(1.0f + erff(h[m][3]*0.70710678118654752f));
    *(float4*)(g + n*HIDDEN + lane*4) = o;                 // coalesced 1KB
  }
}

// ffn2: out = g @ w2 + b2.  Wave per 8 nodes; lane owns out dim `lane`.
// g rows via scalar loads (SGPR operand), w2 rows coalesced 256B.
// ~32 VGPR -> 8 waves/SIMD for latency hiding.
__global__ __launch_bounds__(256) void ffn2_kernel(
    const float* __restrict__ g,
    const float* __restrict__ w2, const float* __restrict__ b2,
    float* __restrict__ out, int n_nodes)
{
  const int wid  = __builtin_amdgcn_readfirstlane(threadIdx.x >> 6);  // wave-uniform
  const int lane = threadIdx.x & 63;
  const long nbase = (long)blockIdx.x * 32 + wid * 8;

  const float* grow[8];
  #pragma unroll
  for (int m = 0; m < 8; ++m) {
    long n = nbase + m; if (n >= n_nodes) n = n_nodes - 1;
    grow[m] = g + n*HIDDEN;           // uniform pointer -> scalar loads
  }
  const float b2v = b2[lane];
  float acc[8];
  #pragma unroll
  for (int m = 0; m < 8; ++m) acc[m] = b2v;

  #pragma unroll 8
  for (int j = 0; j < HIDDEN; ++j) {
    float wv = w2[j*DIM + lane];      // coalesced 256B
    #pragma unroll
    for (int m = 0; m < 8; ++m)
      acc[m] += grow[m][j] * wv;      // SGPR x VGPR FMA
  }
  #pragma unroll
  for (int m = 0; m < 8; ++m) {
    long n = nbase + m;
    if (n < n_nodes) out[n*DIM + lane] = acc[m];
  }
}

// ---------------- launch ----------------
extern "C" void kernel_launch(void* const* d_in, const int* in_sizes, int n_in,
                              void* d_out, int out_size, void* d_ws, size_t ws_size,
                              hipStream_t stream)
{
  const float* x         = (const float*)d_in[0];
  const float* edge_feat = (const float*)d_in[1];
  const float* w_in      = (const float*)d_in[2];
  const float* b_in      = (const float*)d_in[3];
  const float* w_edge    = (const float*)d_in[4];
  const float* b_edge    = (const float*)d_in[5];
  const float* w_att_u   = (const float*)d_in[6];
  const float* b_att_u   = (const float*)d_in[7];
  const float* w_att_v   = (const float*)d_in[8];
  const float* w_att_e   = (const float*)d_in[9];
  const float* b_att_e   = (const float*)d_in[10];
  const float* w_ff1     = (const float*)d_in[11];
  const float* b_ff1     = (const float*)d_in[12];
  const float* w_ff2     = (const float*)d_in[13];
  const float* b_ff2     = (const float*)d_in[14];
  const int*   src       = (const int*)d_in[15];
  const int*   dst       = (const int*)d_in[16];
  float* out = (float*)d_out;

  const int n_nodes = in_sizes[0] / DIM;
  const int n_edges = in_sizes[15];

  char* p = (char*)d_ws;
  auto alloc_f = [&](size_t cnt) { float* r = (float*)p; p += ((cnt*4 + 255) & ~(size_t)255); return r; };
  auto alloc_i = [&](size_t cnt) { int* r = (int*)p;   p += ((cnt*4 + 255) & ~(size_t)255); return r; };
  float* Waug  = alloc_f(64*80);
  float* baug  = alloc_f(80);
  float* wcc   = alloc_f(16);
  float* bcc   = alloc_f(8);
  float* aggb  = alloc_f((size_t)n_nodes*DIM);   // live until ffn1
  float* hbuf  = alloc_f((size_t)n_nodes*DIM);   // dead after attn
  float* subuf = alloc_f((size_t)n_nodes*8);     // dead after attn
  float* svbuf = alloc_f((size_t)n_nodes*8);     // dead after attn
  int* deg     = alloc_i(n_nodes);               // dead after attn
  int* pos     = alloc_i(n_nodes);               // dead after scatter
  int* counter = alloc_i(64);
  int* offb    = alloc_i(n_nodes);               // dead after attn
  int* csr     = alloc_i(n_edges);               // dead after attn
  // g[N,256] aliases the dead-after-attn region starting at hbuf (ffn1 runs
  // after attn has consumed hbuf/subuf/svbuf/deg/off/csr).
  float* gbuf  = hbuf;

  // zero deg, pos, counter in one shot (contiguous in the layout)
  hipMemsetAsync(deg, 0, (size_t)((char*)offb - (char*)deg), stream);

  hipLaunchKernelGGL(prep_kernel, dim3(1), dim3(256), 0, stream,
      w_in, b_in, w_edge, b_edge, w_att_u, b_att_u, w_att_v, w_att_e, b_att_e,
      Waug, baug, wcc, bcc);

  hipLaunchKernelGGL(node_gemm_kernel, dim3((n_nodes+31)/32), dim3(256), 0, stream,
      x, Waug, baug, hbuf, subuf, svbuf, n_nodes);

  hipLaunchKernelGGL(hist_kernel, dim3((n_edges+255)/256), dim3(256), 0, stream,
      dst, deg, n_edges);
  hipLaunchKernelGGL(alloc_kernel, dim3((n_nodes+255)/256), dim3(256), 0, stream,
      deg, offb, counter, n_nodes);
  hipLaunchKernelGGL(scatter_kernel, dim3((n_edges+255)/256), dim3(256), 0, stream,
      dst, offb, pos, csr, n_edges);

  hipLaunchKernelGGL(attn_kernel, dim3((n_nodes+15)/16), dim3(256), 0, stream,
      src, csr, offb, deg, edge_feat, hbuf, subuf, svbuf, wcc, bcc, aggb, n_nodes);

  hipLaunchKernelGGL(ffn1_kernel, dim3((n_nodes+31)/32), dim3(256), 0, stream,
      aggb, w_ff1, b_ff1, gbuf, n_nodes);

  hipLaunchKernelGGL(ffn2_kernel, dim3((n_nodes+31)/32), dim3(256), 0, stream,
      gbuf, w_ff2, b_ff2, out, n_nodes);
}